// Round 2
// baseline (3260.316 us; speedup 1.0000x reference)
//
#include <hip/hip_runtime.h>
#include <hip/hip_bf16.h>

// Problem constants
#define B_ 32
#define T_ 600

typedef __attribute__((ext_vector_type(8))) short short8;
typedef __attribute__((ext_vector_type(4))) float f32x4;
typedef __attribute__((ext_vector_type(4))) unsigned short ushort4v;

static __device__ __forceinline__ unsigned short f2bf(float f) {
    unsigned u = __float_as_uint(f);
    u += 0x7FFFu + ((u >> 16) & 1u);
    return (unsigned short)(u >> 16);
}

// ---------------------------------------------------------------------------
// Fused 1x1-conv GEMM via bf16 MFMA: out[b,o,t] = bn(relu(W @ in + bias)).
// Also (a) folds zeroing of scratch buffers, (b) optional SE time-sum.
template<bool HAS_IN2, bool DO_SSUM>
__global__ __launch_bounds__(256) void gemm_kernel(
    const float* __restrict__ in0, int s0,
    const float* __restrict__ in1,            // b-stride 614400 (x slice)
    const float* __restrict__ Wg, const float* __restrict__ bias,
    const float* __restrict__ bnp, float* __restrict__ out,
    float* __restrict__ ssum,
    float* __restrict__ zbuf, int zn,         // zero zn floats (mid)
    float* __restrict__ zbuf2)                // zero 4096 floats (sbuf) or null
{
    __shared__ unsigned short Al[128][136];   // W[o][c] bf16, +8 pad
    __shared__ unsigned short Bl[64][136];    // in^T [t][c] bf16, +8 pad
    const int tid = threadIdx.x;
    const int b = blockIdx.y;
    const int t0 = blockIdx.x * 64;

    // folded zeroing of scratch (runs before dependent kernels via stream order)
    {
        int fid = (b * gridDim.x + blockIdx.x) * 256 + tid;
        int tot = gridDim.x * B_ * 256;
        for (int idx = fid; idx < zn; idx += tot) zbuf[idx] = 0.f;
        if (zbuf2 != nullptr && fid < 4096) zbuf2[fid] = 0.f;
    }

    // stage A: 128x128 f32 weights -> bf16 LDS
    for (int e = tid; e < 128 * 32; e += 256) {
        int row = e >> 5, c4 = (e & 31) * 4;
        float4 w4 = *(const float4*)&Wg[row * 128 + c4];
        ushort4v u;
        u.x = f2bf(w4.x); u.y = f2bf(w4.y); u.z = f2bf(w4.z); u.w = f2bf(w4.w);
        *(ushort4v*)&Al[row][c4] = u;
    }
    // stage B: in[b, c, t0+t] (+in1) -> Bl[t][c] bf16 (transpose in LDS)
    {
        int t = tid & 63, cb = tid >> 6;
        int gt = t0 + t;
        bool inr = gt < T_;
        const float* p0 = in0 + b * s0 + gt;
        const float* p1 = HAS_IN2 ? (in1 + b * 614400 + gt) : nullptr;
        for (int q = 0; q < 32; q += 8) {
            unsigned short u8[8];
#pragma unroll
            for (int r = 0; r < 8; ++r) {
                int c = cb * 32 + q + r;
                float v = 0.f;
                if (inr) {
                    v = p0[c * T_];
                    if (HAS_IN2) v += p1[c * T_];
                }
                u8[r] = f2bf(v);
            }
            *(short8*)&Bl[t][cb * 32 + q] = *(short8*)u8;
        }
    }
    __syncthreads();

    const int wave = tid >> 6, lane = tid & 63;
    const int mBase = (wave >> 1) * 64, nBase = (wave & 1) * 32;
    const int lr = lane & 15, lq = lane >> 4;

    f32x4 acc[4][2];
#pragma unroll
    for (int mf = 0; mf < 4; ++mf)
#pragma unroll
        for (int nf = 0; nf < 2; ++nf) acc[mf][nf] = {0.f, 0.f, 0.f, 0.f};

#pragma unroll
    for (int kb = 0; kb < 4; ++kb) {
        short8 af[4], bfr[2];
#pragma unroll
        for (int mf = 0; mf < 4; ++mf)
            af[mf] = *(const short8*)&Al[mBase + mf * 16 + lr][kb * 32 + lq * 8];
#pragma unroll
        for (int nf = 0; nf < 2; ++nf)
            bfr[nf] = *(const short8*)&Bl[nBase + nf * 16 + lr][kb * 32 + lq * 8];
#pragma unroll
        for (int mf = 0; mf < 4; ++mf)
#pragma unroll
            for (int nf = 0; nf < 2; ++nf)
                acc[mf][nf] = __builtin_amdgcn_mfma_f32_16x16x32_bf16(
                    af[mf], bfr[nf], acc[mf][nf], 0, 0, 0);
    }

    // epilogue: bias -> relu -> bn -> store (+ optional SE partial time-sum)
#pragma unroll
    for (int mf = 0; mf < 4; ++mf) {
#pragma unroll
        for (int i = 0; i < 4; ++i) {
            int o = mBase + mf * 16 + lq * 4 + i;
            float g = bnp[o], be = bnp[128 + o], m = bnp[256 + o], vv = bnp[384 + o];
            float sc = g * rsqrtf(vv + 1e-5f), sh = be - m * sc;
            float bs = bias[o];
            float psum = 0.f;
#pragma unroll
            for (int nf = 0; nf < 2; ++nf) {
                int t = t0 + nBase + nf * 16 + lr;
                float v = fmaxf(acc[mf][nf][i] + bs, 0.f) * sc + sh;
                if (t < T_) { out[(b * 128 + o) * T_ + t] = v; psum += v; }
            }
            if (DO_SSUM) {
                psum += __shfl_xor(psum, 1);
                psum += __shfl_xor(psum, 2);
                psum += __shfl_xor(psum, 4);
                psum += __shfl_xor(psum, 8);
                if (lr == 0) atomicAdd(&ssum[b * 128 + o], psum);
            }
        }
    }
}

// ---------------------------------------------------------------------------
// Inner Res2 chain, per-slice-chain parallel. Chain c: c==0 -> slice from
// out1 ch112..127 (convs 0..6); c>=1 -> out1 ch 16(c-1).. (convs (c-1)..6).
// Each wg: one (b, t-tile, chain); state 16ch x extent in LDS, ping-pong.
// Weighted-scale contributions accumulate into mid via atomicAdd.
constexpr int TI = 100;     // 600 = 6 * 100 (exact)
constexpr int ROWL = 134;   // >= 128 + 4 slack, even, ==2 mod 4

__global__ __launch_bounds__(128, 2) void inner_kernel(
    const float* __restrict__ out1, float* __restrict__ mid,
    const float* __restrict__ cwB, const float* __restrict__ cbB,
    const float* __restrict__ ibnB,
    const float* __restrict__ ws0, const float* __restrict__ ws1,
    const float* __restrict__ ws2, const float* __restrict__ ws3,
    const float* __restrict__ ws4, const float* __restrict__ ws5,
    const float* __restrict__ ws6)
{
    __shared__ float st[2][16][ROWL];
    const int tid = threadIdx.x;
    const int tile = blockIdx.x;   // 0..5
    const int c = blockIdx.y;      // chain 0..7
    const int b = blockIdx.z;

    const int j0 = (c <= 1) ? 0 : (c - 1);
    const int nconv = 7 - j0;
    const int halo = 2 * nconv;
    const int X = TI + 2 * halo;   // <= 128
    const int ch0 = (c == 0) ? 112 : 16 * (c - 1);
    const int t0g = tile * TI - halo;

    // load initial state (zero outside [0,T)); chain 0 also copies its
    // central region to mid ch 112..127 (plain store, sole writer).
    for (int e = tid; e < 16 * X; e += 128) {
        int i = e / X, t = e - i * X;
        int g = t0g + t;
        float v = ((unsigned)g < T_) ? out1[(b * 128 + ch0 + i) * T_ + g] : 0.f;
        st[0][i][t] = v;
        if (c == 0 && t >= halo && t < halo + TI)
            mid[(b * 128 + 112 + i) * T_ + g] = v;
    }
    __syncthreads();

    const int op = tid & 7, tg = tid >> 3;   // 8 ch-pairs x 16 t-groups
    int cur = 0;
    for (int j = j0; j < 7; ++j) {
        const int k = j - j0;
        const int olo = 2 * k + 2, ohi = X - 2 * k - 2;

        // per-step parameters (registers; i-loop fully unrolled -> static idx)
        float wA[16][3], wB[16][3];
        const float* wbase = &cwB[(j * 16 + op) * 48];
        const float* wbase2 = wbase + 8 * 48;
#pragma unroll
        for (int i = 0; i < 16; ++i)
#pragma unroll
            for (int kk = 0; kk < 3; ++kk) {
                wA[i][kk] = wbase[i * 3 + kk];
                wB[i][kk] = wbase2[i * 3 + kk];
            }
        const float biasA = cbB[j * 16 + op], biasB = cbB[j * 16 + op + 8];
        float gA = ibnB[(j * 4 + 0) * 16 + op], bA = ibnB[(j * 4 + 1) * 16 + op];
        float mA = ibnB[(j * 4 + 2) * 16 + op], vA = ibnB[(j * 4 + 3) * 16 + op];
        float gB = ibnB[(j * 4 + 0) * 16 + op + 8], bB = ibnB[(j * 4 + 1) * 16 + op + 8];
        float mB = ibnB[(j * 4 + 2) * 16 + op + 8], vB = ibnB[(j * 4 + 3) * 16 + op + 8];
        float iscA = gA * rsqrtf(vA + 1e-5f), ishA = bA - mA * iscA;
        float iscB = gB * rsqrtf(vB + 1e-5f), ishB = bB - mB * iscB;
        const float* wp;
        switch (j) {
            case 0: wp = ws0; break; case 1: wp = ws1; break;
            case 2: wp = ws2; break; case 3: wp = ws3; break;
            case 4: wp = ws4; break; case 5: wp = ws5; break;
            default: wp = ws6; break;
        }
        const float wsv = wp[c];

        const int t8 = olo + tg * 8;
        const int nxt = cur ^ 1;
        if (t8 < ohi) {
            float accA[8], accB[8];
#pragma unroll
            for (int d = 0; d < 8; ++d) { accA[d] = biasA; accB[d] = biasB; }
#pragma unroll
            for (int i = 0; i < 16; ++i) {
                const float* row = &st[cur][i][0];
                float v[12];
#pragma unroll
                for (int m = 0; m < 6; ++m) {
                    float2 r2 = *(const float2*)&row[t8 - 2 + 2 * m];
                    v[2 * m] = r2.x; v[2 * m + 1] = r2.y;
                }
#pragma unroll
                for (int d = 0; d < 8; ++d) {
                    accA[d] += wA[i][0] * v[d] + wA[i][1] * v[d + 2] + wA[i][2] * v[d + 4];
                    accB[d] += wB[i][0] * v[d] + wB[i][1] * v[d + 2] + wB[i][2] * v[d + 4];
                }
            }
#pragma unroll
            for (int d = 0; d < 8; ++d) {
                int t = t8 + d;
                int g = t0g + t;
                bool ok = (t < ohi) && ((unsigned)g < T_);
                float va = ok ? fmaxf(accA[d], 0.f) * iscA + ishA : 0.f;
                float vb = ok ? fmaxf(accB[d], 0.f) * iscB + ishB : 0.f;
                st[nxt][op][t] = va;
                st[nxt][op + 8][t] = vb;
                if (ok && t >= halo && t < halo + TI) {
                    atomicAdd(&mid[(b * 128 + 16 * j + op) * T_ + g], wsv * va);
                    atomicAdd(&mid[(b * 128 + 16 * j + op + 8) * T_ + g], wsv * vb);
                }
            }
        }
        __syncthreads();
        cur = nxt;
    }
}

// ---------------------------------------------------------------------------
// SE excitation: s2 = sigmoid(W2 relu(W1 (ssum/T) + b1) + b2)
__global__ __launch_bounds__(128) void se_kernel(
    const float* __restrict__ ssum, const float* __restrict__ w1se,
    const float* __restrict__ b1se, const float* __restrict__ w2se,
    const float* __restrict__ b2se, float* __restrict__ s2b)
{
    __shared__ float sL[128], hL[16];
    const int tid = threadIdx.x, b = blockIdx.x;
    sL[tid] = ssum[b * 128 + tid] * (1.f / 600.f);
    __syncthreads();
    if (tid < 16) {
        float a = b1se[tid];
        for (int c = 0; c < 128; ++c) a += w1se[tid * 128 + c] * sL[c];
        hL[tid] = fmaxf(a, 0.f);
    }
    __syncthreads();
    float a = b2se[tid];
#pragma unroll
    for (int q = 0; q < 16; ++q) a += w2se[tid * 16 + q] * hL[q];
    s2b[b * 128 + tid] = 1.f / (1.f + expf(-a));
}

// ---------------------------------------------------------------------------
// Elementwise tail: y = out3*s2 + residual; sp = obn(relu(y)); store sp;
// pooled[b, chOff+c] += mean_t relu(fbn(sp)).
template<bool HAS_R2>
__global__ __launch_bounds__(256) void fuse_kernel(
    const float* __restrict__ out3, const float* __restrict__ s2b,
    const float* __restrict__ res0, int r0s,
    const float* __restrict__ res1,
    const float* __restrict__ obnp, const float* __restrict__ fbnp, int chOff,
    float* __restrict__ spOut, float* __restrict__ pooled)
{
    const int tid = threadIdx.x;
    const int row = blockIdx.x * 4 + (tid >> 6);
    const int lane = tid & 63;
    const int b = row >> 7, c = row & 127;
    const float s2v = s2b[b * 128 + c];
    float g = obnp[c], bb = obnp[128 + c], m = obnp[256 + c], v = obnp[384 + c];
    float osc = g * rsqrtf(v + 1e-5f), osh = bb - m * osc;
    int fc = chOff + c;
    float fg = fbnp[fc], fb2 = fbnp[1024 + fc], fm = fbnp[2048 + fc], fv = fbnp[3072 + fc];
    float fsc = fg * rsqrtf(fv + 1e-5f), fsh = fb2 - fm * fsc;
    int base = (b * 128 + c) * T_;
    float psum = 0.f;
    for (int t = lane; t < T_; t += 64) {
        float o3 = out3[base + t];
        float r = res0[b * r0s + c * T_ + t];
        if (HAS_R2) r += res1[b * 614400 + c * T_ + t];
        float fin = o3 * s2v + r;
        float sp = fmaxf(fin, 0.f) * osc + osh;
        spOut[base + t] = sp;
        psum += fmaxf(sp * fsc + fsh, 0.f);
    }
    for (int mo = 32; mo > 0; mo >>= 1) psum += __shfl_xor(psum, mo);
    if (lane == 0) pooled[b * 1024 + fc] = psum * (1.f / 600.f);
}

// pooled tail for x channels 896..1023
__global__ __launch_bounds__(256) void pooledx_kernel(
    const float* __restrict__ x, const float* __restrict__ fbnp,
    float* __restrict__ pooled)
{
    const int tid = threadIdx.x;
    const int row = blockIdx.x * 4 + (tid >> 6);
    const int lane = tid & 63;
    const int b = row >> 7, c = row & 127;
    int fc = 896 + c;
    float fg = fbnp[fc], fb2 = fbnp[1024 + fc], fm = fbnp[2048 + fc], fv = fbnp[3072 + fc];
    float fsc = fg * rsqrtf(fv + 1e-5f), fsh = fb2 - fm * fsc;
    int base = (b * 1024 + fc) * T_;
    float psum = 0.f;
    for (int t = lane; t < T_; t += 64)
        psum += fmaxf(x[base + t] * fsc + fsh, 0.f);
    for (int mo = 32; mo > 0; mo >>= 1) psum += __shfl_xor(psum, mo);
    if (lane == 0) pooled[b * 1024 + fc] = psum * (1.f / 600.f);
}

// final classifier
__global__ __launch_bounds__(256) void logits_kernel(
    const float* __restrict__ pooled, const float* __restrict__ fcw,
    const float* __restrict__ fcb, float* __restrict__ outp)
{
    __shared__ float red[256];
    const int tid = threadIdx.x;
    const int item = tid & 63, part = tid >> 6;
    const int b = item >> 1, cls = item & 1;
    float a = 0.f;
    for (int c = part * 256; c < part * 256 + 256; ++c)
        a += pooled[b * 1024 + c] * fcw[cls * 1024 + c];
    red[tid] = a;
    __syncthreads();
    if (tid < 64)
        outp[b * 2 + cls] = red[tid] + red[tid + 64] + red[tid + 128] + red[tid + 192] + fcb[cls];
}

// ---------------------------------------------------------------------------
extern "C" void kernel_launch(void* const* d_in, const int* in_sizes, int n_in,
                              void* d_out, int out_size, void* d_ws, size_t ws_size,
                              hipStream_t stream) {
    const float* x    = (const float*)d_in[0];
    const float* w1   = (const float*)d_in[1];
    const float* b1   = (const float*)d_in[2];
    const float* bn1  = (const float*)d_in[3];
    const float* cw   = (const float*)d_in[4];
    const float* cb   = (const float*)d_in[5];
    const float* ibn  = (const float*)d_in[6];
    const float* w3   = (const float*)d_in[7];
    const float* b3   = (const float*)d_in[8];
    const float* bn3  = (const float*)d_in[9];
    const float* se1w = (const float*)d_in[10];
    const float* se1b = (const float*)d_in[11];
    const float* se2w = (const float*)d_in[12];
    const float* se2b = (const float*)d_in[13];
    const float* obn  = (const float*)d_in[14];
    const float* fbn  = (const float*)d_in[15];
    const float* fcw  = (const float*)d_in[16];
    const float* fcb  = (const float*)d_in[17];
    const float* wsp[7] = {(const float*)d_in[18], (const float*)d_in[19],
                           (const float*)d_in[20], (const float*)d_in[21],
                           (const float*)d_in[22], (const float*)d_in[23],
                           (const float*)d_in[24]};

    float* ws = (float*)d_ws;
    const int NT = 128 * T_ * B_;          // 2,457,600 floats per (B,128,T)
    float* out1   = ws;
    float* mid    = out1 + NT;
    float* out3   = mid + NT;
    float* spA    = out3 + NT;
    float* spB    = spA + NT;
    float* sbuf   = spB + NT;              // 7*4096
    float* s2b    = sbuf + 7 * 4096;       // 4096
    float* pooled = s2b + 4096;            // 32768

    pooledx_kernel<<<1024, 256, 0, stream>>>(x, fbn, pooled);

    dim3 gGrid(10, B_);        // ceil(600/64) x B
    dim3 iGrid(6, 8, B_);      // t-tiles x chains x B

    float* spBufs[2] = {spA, spB};
    for (int i = 0; i < 7; ++i) {
        float* spOut = spBufs[i & 1];
        const float* spIn = spBufs[(i & 1) ^ 1];

        // gemm1 also zeroes mid + this block's SE accumulator
        if (i == 0)
            gemm_kernel<false, false><<<gGrid, 256, 0, stream>>>(
                x, 614400, nullptr, w1, b1, bn1, out1, nullptr,
                mid, NT, sbuf + i * 4096);
        else
            gemm_kernel<true, false><<<gGrid, 256, 0, stream>>>(
                spIn, 76800, x + i * 76800,
                w1 + i * 16384, b1 + i * 128, bn1 + i * 512, out1, nullptr,
                mid, NT, sbuf + i * 4096);

        inner_kernel<<<iGrid, 128, 0, stream>>>(
            out1, mid, cw + i * 5376, cb + i * 112, ibn + i * 448,
            wsp[0] + 2 * i, wsp[1] + 3 * i, wsp[2] + 4 * i, wsp[3] + 5 * i,
            wsp[4] + 6 * i, wsp[5] + 7 * i, wsp[6] + 8 * i);

        gemm_kernel<false, true><<<gGrid, 256, 0, stream>>>(
            mid, 76800, nullptr,
            w3 + i * 16384, b3 + i * 128, bn3 + i * 512, out3, sbuf + i * 4096,
            nullptr, 0, nullptr);

        se_kernel<<<B_, 128, 0, stream>>>(
            sbuf + i * 4096, se1w + i * 2048, se1b + i * 16,
            se2w + i * 2048, se2b + i * 128, s2b);

        if (i == 0)
            fuse_kernel<false><<<1024, 256, 0, stream>>>(
                out3, s2b, x, 614400, nullptr, obn, fbn, 0, spOut, pooled);
        else
            fuse_kernel<true><<<1024, 256, 0, stream>>>(
                out3, s2b, spIn, 76800, x + i * 76800,
                obn + i * 512, fbn, i * 128, spOut, pooled);
    }

    logits_kernel<<<1, 256, 0, stream>>>(pooled, fcw, fcb, (float*)d_out);
}

// Round 3
// 1627.930 us; speedup vs baseline: 2.0027x; 2.0027x over previous
//
#include <hip/hip_runtime.h>
#include <hip/hip_bf16.h>

// Problem constants
#define B_ 32
#define T_ 600

typedef __attribute__((ext_vector_type(8))) short short8;
typedef __attribute__((ext_vector_type(4))) float f32x4;
typedef __attribute__((ext_vector_type(4))) unsigned short ushort4v;

static __device__ __forceinline__ unsigned short f2bf(float f) {
    unsigned u = __float_as_uint(f);
    u += 0x7FFFu + ((u >> 16) & 1u);
    return (unsigned short)(u >> 16);
}
static __device__ __forceinline__ float bf2f(unsigned short u) {
    return __uint_as_float(((unsigned)u) << 16);
}

// ---------------------------------------------------------------------------
// Fused 1x1-conv GEMM via bf16 MFMA: out[b,o,t] = bn(relu(W @ in + bias)).
// Optionally zeroes a 4096-float buffer (SE accumulator) and accumulates
// per-(b,o) time-sums for SE.
template<bool HAS_IN2, bool DO_SSUM>
__global__ __launch_bounds__(256) void gemm_kernel(
    const float* __restrict__ in0, int s0,
    const float* __restrict__ in1,            // b-stride 614400 (x slice)
    const float* __restrict__ Wg, const float* __restrict__ bias,
    const float* __restrict__ bnp, float* __restrict__ out,
    float* __restrict__ ssum,
    float* __restrict__ zbuf4096)
{
    __shared__ unsigned short Al[128][136];   // W[o][c] bf16, +8 pad
    __shared__ unsigned short Bl[64][136];    // in^T [t][c] bf16, +8 pad
    const int tid = threadIdx.x;
    const int b = blockIdx.y;
    const int t0 = blockIdx.x * 64;

    if (zbuf4096 != nullptr) {
        int fid = (b * gridDim.x + blockIdx.x) * 256 + tid;
        if (fid < 4096) zbuf4096[fid] = 0.f;
    }

    // stage A: 128x128 f32 weights -> bf16 LDS
    for (int e = tid; e < 128 * 32; e += 256) {
        int row = e >> 5, c4 = (e & 31) * 4;
        float4 w4 = *(const float4*)&Wg[row * 128 + c4];
        ushort4v u;
        u.x = f2bf(w4.x); u.y = f2bf(w4.y); u.z = f2bf(w4.z); u.w = f2bf(w4.w);
        *(ushort4v*)&Al[row][c4] = u;
    }
    // stage B: in[b, c, t0+t] (+in1) -> Bl[t][c] bf16 (transpose in LDS)
    {
        int t = tid & 63, cb = tid >> 6;
        int gt = t0 + t;
        bool inr = gt < T_;
        const float* p0 = in0 + b * s0 + gt;
        const float* p1 = HAS_IN2 ? (in1 + b * 614400 + gt) : nullptr;
        for (int q = 0; q < 32; q += 8) {
            unsigned short u8[8];
#pragma unroll
            for (int r = 0; r < 8; ++r) {
                int c = cb * 32 + q + r;
                float v = 0.f;
                if (inr) {
                    v = p0[c * T_];
                    if (HAS_IN2) v += p1[c * T_];
                }
                u8[r] = f2bf(v);
            }
            *(short8*)&Bl[t][cb * 32 + q] = *(short8*)u8;
        }
    }
    __syncthreads();

    const int wave = tid >> 6, lane = tid & 63;
    const int mBase = (wave >> 1) * 64, nBase = (wave & 1) * 32;
    const int lr = lane & 15, lq = lane >> 4;

    f32x4 acc[4][2];
#pragma unroll
    for (int mf = 0; mf < 4; ++mf)
#pragma unroll
        for (int nf = 0; nf < 2; ++nf) acc[mf][nf] = {0.f, 0.f, 0.f, 0.f};

#pragma unroll
    for (int kb = 0; kb < 4; ++kb) {
        short8 af[4], bfr[2];
#pragma unroll
        for (int mf = 0; mf < 4; ++mf)
            af[mf] = *(const short8*)&Al[mBase + mf * 16 + lr][kb * 32 + lq * 8];
#pragma unroll
        for (int nf = 0; nf < 2; ++nf)
            bfr[nf] = *(const short8*)&Bl[nBase + nf * 16 + lr][kb * 32 + lq * 8];
#pragma unroll
        for (int mf = 0; mf < 4; ++mf)
#pragma unroll
            for (int nf = 0; nf < 2; ++nf)
                acc[mf][nf] = __builtin_amdgcn_mfma_f32_16x16x32_bf16(
                    af[mf], bfr[nf], acc[mf][nf], 0, 0, 0);
    }

    // epilogue: bias -> relu -> bn -> store (+ optional SE partial time-sum)
#pragma unroll
    for (int mf = 0; mf < 4; ++mf) {
#pragma unroll
        for (int i = 0; i < 4; ++i) {
            int o = mBase + mf * 16 + lq * 4 + i;
            float g = bnp[o], be = bnp[128 + o], m = bnp[256 + o], vv = bnp[384 + o];
            float sc = g * rsqrtf(vv + 1e-5f), sh = be - m * sc;
            float bs = bias[o];
            float psum = 0.f;
#pragma unroll
            for (int nf = 0; nf < 2; ++nf) {
                int t = t0 + nBase + nf * 16 + lr;
                float v = fmaxf(acc[mf][nf][i] + bs, 0.f) * sc + sh;
                if (t < T_) { out[(b * 128 + o) * T_ + t] = v; psum += v; }
            }
            if (DO_SSUM) {
                psum += __shfl_xor(psum, 1);
                psum += __shfl_xor(psum, 2);
                psum += __shfl_xor(psum, 4);
                psum += __shfl_xor(psum, 8);
                if (lr == 0) atomicAdd(&ssum[b * 128 + o], psum);
            }
        }
    }
}

// ---------------------------------------------------------------------------
// Inner Res2 chain, per-slice-chain parallel, NO global atomics.
// Chain c: c==0 -> out1 ch112..127 (convs 0..6); c>=1 -> out1 ch 16(c-1)..
// (convs (c-1)..6). Each wg: one (b, t-tile, chain). Per conv step the new
// state's central TI columns are stored (bf16) to chainout[pair(j,c)].
constexpr int TI = 100;     // 600 = 6 * 100 (exact)
constexpr int ROWL = 134;   // >= 128 + slack

__global__ __launch_bounds__(128, 2) void inner_kernel(
    const float* __restrict__ out1, float* __restrict__ mid,
    unsigned short* __restrict__ chainout,
    const float* __restrict__ cwB, const float* __restrict__ cbB,
    const float* __restrict__ ibnB)
{
    __shared__ float st[2][16][ROWL];
    const int tid = threadIdx.x;
    const int tile = blockIdx.x;   // 0..5
    const int c = blockIdx.y;      // chain 0..7
    const int b = blockIdx.z;

    const int j0 = (c <= 1) ? 0 : (c - 1);
    const int nconv = 7 - j0;
    const int halo = 2 * nconv;
    const int X = TI + 2 * halo;   // <= 128
    const int ch0 = (c == 0) ? 112 : 16 * (c - 1);
    const int t0g = tile * TI - halo;

    // load initial state (zero outside [0,T)); chain 0 also copies its
    // central region to mid ch 112..127 (plain store, sole writer).
    for (int e = tid; e < 16 * X; e += 128) {
        int i = e / X, t = e - i * X;
        int g = t0g + t;
        float v = ((unsigned)g < T_) ? out1[(b * 128 + ch0 + i) * T_ + g] : 0.f;
        st[0][i][t] = v;
        if (c == 0 && t >= halo && t < halo + TI)
            mid[(b * 128 + 112 + i) * T_ + g] = v;
    }
    __syncthreads();

    const int op = tid & 7, tg = tid >> 3;   // 8 ch-pairs x 16 t-groups
    int cur = 0;
    for (int j = j0; j < 7; ++j) {
        const int k = j - j0;
        const int olo = 2 * k + 2, ohi = X - 2 * k - 2;

        float wA[16][3], wB[16][3];
        const float* wbase = &cwB[(j * 16 + op) * 48];
        const float* wbase2 = wbase + 8 * 48;
#pragma unroll
        for (int i = 0; i < 16; ++i)
#pragma unroll
            for (int kk = 0; kk < 3; ++kk) {
                wA[i][kk] = wbase[i * 3 + kk];
                wB[i][kk] = wbase2[i * 3 + kk];
            }
        const float biasA = cbB[j * 16 + op], biasB = cbB[j * 16 + op + 8];
        float gA = ibnB[(j * 4 + 0) * 16 + op], bA = ibnB[(j * 4 + 1) * 16 + op];
        float mA = ibnB[(j * 4 + 2) * 16 + op], vA = ibnB[(j * 4 + 3) * 16 + op];
        float gB = ibnB[(j * 4 + 0) * 16 + op + 8], bB = ibnB[(j * 4 + 1) * 16 + op + 8];
        float mB = ibnB[(j * 4 + 2) * 16 + op + 8], vB = ibnB[(j * 4 + 3) * 16 + op + 8];
        float iscA = gA * rsqrtf(vA + 1e-5f), ishA = bA - mA * iscA;
        float iscB = gB * rsqrtf(vB + 1e-5f), ishB = bB - mB * iscB;

        const int t8 = olo + tg * 8;
        const int nxt = cur ^ 1;
        if (t8 < ohi) {
            float accA[8], accB[8];
#pragma unroll
            for (int d = 0; d < 8; ++d) { accA[d] = biasA; accB[d] = biasB; }
#pragma unroll
            for (int i = 0; i < 16; ++i) {
                const float* row = &st[cur][i][0];
                float v[12];
#pragma unroll
                for (int m = 0; m < 6; ++m) {
                    float2 r2 = *(const float2*)&row[t8 - 2 + 2 * m];
                    v[2 * m] = r2.x; v[2 * m + 1] = r2.y;
                }
#pragma unroll
                for (int d = 0; d < 8; ++d) {
                    accA[d] += wA[i][0] * v[d] + wA[i][1] * v[d + 2] + wA[i][2] * v[d + 4];
                    accB[d] += wB[i][0] * v[d] + wB[i][1] * v[d + 2] + wB[i][2] * v[d + 4];
                }
            }
#pragma unroll
            for (int d = 0; d < 8; ++d) {
                int t = t8 + d;
                int g = t0g + t;
                bool ok = (t < ohi) && ((unsigned)g < T_);
                float va = ok ? fmaxf(accA[d], 0.f) * iscA + ishA : 0.f;
                float vb = ok ? fmaxf(accB[d], 0.f) * iscB + ishB : 0.f;
                st[nxt][op][t] = va;
                st[nxt][op + 8][t] = vb;
            }
        }
        __syncthreads();
        cur = nxt;

        // store central region of the new state to chainout (bf16, coalesced)
        {
            const int pair = j * (j + 3) / 2 + c;
            unsigned short* dst = chainout + ((size_t)(pair * B_ + b) * 16) * T_
                                + tile * TI;
            for (int e = tid; e < 16 * TI; e += 128) {
                int i = e / TI, tt = e - i * TI;
                dst[i * T_ + tt] = f2bf(st[cur][i][halo + tt]);
            }
        }
    }
}

// ---------------------------------------------------------------------------
// Weighted scale-sum: mid[b,16j+i,t] = sum_s ws_j[s] * chainout[pair0+s][b,i,t]
__global__ __launch_bounds__(256) void wsum_kernel(
    const unsigned short* __restrict__ chainout, float* __restrict__ mid,
    const float* __restrict__ ws0, const float* __restrict__ ws1,
    const float* __restrict__ ws2, const float* __restrict__ ws3,
    const float* __restrict__ ws4, const float* __restrict__ ws5,
    const float* __restrict__ ws6)
{
    const int j = blockIdx.x, b = blockIdx.y;
    const int nsl = j + 2, pair0 = j * (j + 3) / 2;
    const float* wp;
    switch (j) {
        case 0: wp = ws0; break; case 1: wp = ws1; break;
        case 2: wp = ws2; break; case 3: wp = ws3; break;
        case 4: wp = ws4; break; case 5: wp = ws5; break;
        default: wp = ws6; break;
    }
    float wv[8];
    for (int s = 0; s < 8; ++s) wv[s] = (s < nsl) ? wp[s] : 0.f;

    const unsigned short* src = chainout + (size_t)pair0 * B_ * 9600 + (size_t)b * 9600;
    float* dst = mid + ((size_t)b * 128 + 16 * j) * T_;
    for (int e = threadIdx.x; e < 16 * T_; e += 256) {
        float acc = 0.f;
        for (int s = 0; s < nsl; ++s)
            acc += wv[s] * bf2f(src[(size_t)s * B_ * 9600 + e]);
        dst[e] = acc;
    }
}

// ---------------------------------------------------------------------------
// SE excitation: s2 = sigmoid(W2 relu(W1 (ssum/T) + b1) + b2)
__global__ __launch_bounds__(128) void se_kernel(
    const float* __restrict__ ssum, const float* __restrict__ w1se,
    const float* __restrict__ b1se, const float* __restrict__ w2se,
    const float* __restrict__ b2se, float* __restrict__ s2b)
{
    __shared__ float sL[128], hL[16];
    const int tid = threadIdx.x, b = blockIdx.x;
    sL[tid] = ssum[b * 128 + tid] * (1.f / 600.f);
    __syncthreads();
    if (tid < 16) {
        float a = b1se[tid];
        for (int c = 0; c < 128; ++c) a += w1se[tid * 128 + c] * sL[c];
        hL[tid] = fmaxf(a, 0.f);
    }
    __syncthreads();
    float a = b2se[tid];
#pragma unroll
    for (int q = 0; q < 16; ++q) a += w2se[tid * 16 + q] * hL[q];
    s2b[b * 128 + tid] = 1.f / (1.f + expf(-a));
}

// ---------------------------------------------------------------------------
// Elementwise tail: y = out3*s2 + residual; sp = obn(relu(y)); store sp;
// pooled[b, chOff+c] = mean_t relu(fbn(sp)).
template<bool HAS_R2>
__global__ __launch_bounds__(256) void fuse_kernel(
    const float* __restrict__ out3, const float* __restrict__ s2b,
    const float* __restrict__ res0, int r0s,
    const float* __restrict__ res1,
    const float* __restrict__ obnp, const float* __restrict__ fbnp, int chOff,
    float* __restrict__ spOut, float* __restrict__ pooled)
{
    const int tid = threadIdx.x;
    const int row = blockIdx.x * 4 + (tid >> 6);
    const int lane = tid & 63;
    const int b = row >> 7, c = row & 127;
    const float s2v = s2b[b * 128 + c];
    float g = obnp[c], bb = obnp[128 + c], m = obnp[256 + c], v = obnp[384 + c];
    float osc = g * rsqrtf(v + 1e-5f), osh = bb - m * osc;
    int fc = chOff + c;
    float fg = fbnp[fc], fb2 = fbnp[1024 + fc], fm = fbnp[2048 + fc], fv = fbnp[3072 + fc];
    float fsc = fg * rsqrtf(fv + 1e-5f), fsh = fb2 - fm * fsc;
    int base = (b * 128 + c) * T_;
    float psum = 0.f;
    for (int t = lane; t < T_; t += 64) {
        float o3 = out3[base + t];
        float r = res0[b * r0s + c * T_ + t];
        if (HAS_R2) r += res1[b * 614400 + c * T_ + t];
        float fin = o3 * s2v + r;
        float sp = fmaxf(fin, 0.f) * osc + osh;
        spOut[base + t] = sp;
        psum += fmaxf(sp * fsc + fsh, 0.f);
    }
    for (int mo = 32; mo > 0; mo >>= 1) psum += __shfl_xor(psum, mo);
    if (lane == 0) pooled[b * 1024 + fc] = psum * (1.f / 600.f);
}

// pooled tail for x channels 896..1023
__global__ __launch_bounds__(256) void pooledx_kernel(
    const float* __restrict__ x, const float* __restrict__ fbnp,
    float* __restrict__ pooled)
{
    const int tid = threadIdx.x;
    const int row = blockIdx.x * 4 + (tid >> 6);
    const int lane = tid & 63;
    const int b = row >> 7, c = row & 127;
    int fc = 896 + c;
    float fg = fbnp[fc], fb2 = fbnp[1024 + fc], fm = fbnp[2048 + fc], fv = fbnp[3072 + fc];
    float fsc = fg * rsqrtf(fv + 1e-5f), fsh = fb2 - fm * fsc;
    int base = (b * 1024 + fc) * T_;
    float psum = 0.f;
    for (int t = lane; t < T_; t += 64)
        psum += fmaxf(x[base + t] * fsc + fsh, 0.f);
    for (int mo = 32; mo > 0; mo >>= 1) psum += __shfl_xor(psum, mo);
    if (lane == 0) pooled[b * 1024 + fc] = psum * (1.f / 600.f);
}

// final classifier
__global__ __launch_bounds__(256) void logits_kernel(
    const float* __restrict__ pooled, const float* __restrict__ fcw,
    const float* __restrict__ fcb, float* __restrict__ outp)
{
    __shared__ float red[256];
    const int tid = threadIdx.x;
    const int item = tid & 63, part = tid >> 6;
    const int b = item >> 1, cls = item & 1;
    float a = 0.f;
    for (int c = part * 256; c < part * 256 + 256; ++c)
        a += pooled[b * 1024 + c] * fcw[cls * 1024 + c];
    red[tid] = a;
    __syncthreads();
    if (tid < 64)
        outp[b * 2 + cls] = red[tid] + red[tid + 64] + red[tid + 128] + red[tid + 192] + fcb[cls];
}

// ---------------------------------------------------------------------------
extern "C" void kernel_launch(void* const* d_in, const int* in_sizes, int n_in,
                              void* d_out, int out_size, void* d_ws, size_t ws_size,
                              hipStream_t stream) {
    const float* x    = (const float*)d_in[0];
    const float* w1   = (const float*)d_in[1];
    const float* b1   = (const float*)d_in[2];
    const float* bn1  = (const float*)d_in[3];
    const float* cw   = (const float*)d_in[4];
    const float* cb   = (const float*)d_in[5];
    const float* ibn  = (const float*)d_in[6];
    const float* w3   = (const float*)d_in[7];
    const float* b3   = (const float*)d_in[8];
    const float* bn3  = (const float*)d_in[9];
    const float* se1w = (const float*)d_in[10];
    const float* se1b = (const float*)d_in[11];
    const float* se2w = (const float*)d_in[12];
    const float* se2b = (const float*)d_in[13];
    const float* obn  = (const float*)d_in[14];
    const float* fbn  = (const float*)d_in[15];
    const float* fcw  = (const float*)d_in[16];
    const float* fcb  = (const float*)d_in[17];
    const float* wsp[7] = {(const float*)d_in[18], (const float*)d_in[19],
                           (const float*)d_in[20], (const float*)d_in[21],
                           (const float*)d_in[22], (const float*)d_in[23],
                           (const float*)d_in[24]};

    float* ws = (float*)d_ws;
    const int NT = 128 * T_ * B_;          // 2,457,600 floats per (B,128,T)
    float* out1   = ws;
    float* mid    = out1 + NT;
    float* out3   = mid + NT;
    float* spA    = out3 + NT;
    float* spB    = spA + NT;
    float* sbuf   = spB + NT;              // 7*4096
    float* s2b    = sbuf + 7 * 4096;       // 4096
    float* pooled = s2b + 4096;            // 32768
    unsigned short* chainout = (unsigned short*)(pooled + 32768); // 35*32*9600 ushort

    pooledx_kernel<<<1024, 256, 0, stream>>>(x, fbn, pooled);

    dim3 gGrid(10, B_);        // ceil(600/64) x B
    dim3 iGrid(6, 8, B_);      // t-tiles x chains x B
    dim3 wGrid(7, B_);         // ch-groups x B

    float* spBufs[2] = {spA, spB};
    for (int i = 0; i < 7; ++i) {
        float* spOut = spBufs[i & 1];
        const float* spIn = spBufs[(i & 1) ^ 1];

        // gemm1 also zeroes this block's SE accumulator
        if (i == 0)
            gemm_kernel<false, false><<<gGrid, 256, 0, stream>>>(
                x, 614400, nullptr, w1, b1, bn1, out1, nullptr,
                sbuf + i * 4096);
        else
            gemm_kernel<true, false><<<gGrid, 256, 0, stream>>>(
                spIn, 76800, x + i * 76800,
                w1 + i * 16384, b1 + i * 128, bn1 + i * 512, out1, nullptr,
                sbuf + i * 4096);

        inner_kernel<<<iGrid, 128, 0, stream>>>(
            out1, mid, chainout, cw + i * 5376, cb + i * 112, ibn + i * 448);

        wsum_kernel<<<wGrid, 256, 0, stream>>>(
            chainout, mid,
            wsp[0] + 2 * i, wsp[1] + 3 * i, wsp[2] + 4 * i, wsp[3] + 5 * i,
            wsp[4] + 6 * i, wsp[5] + 7 * i, wsp[6] + 8 * i);

        gemm_kernel<false, true><<<gGrid, 256, 0, stream>>>(
            mid, 76800, nullptr,
            w3 + i * 16384, b3 + i * 128, bn3 + i * 512, out3, sbuf + i * 4096,
            nullptr);

        se_kernel<<<B_, 128, 0, stream>>>(
            sbuf + i * 4096, se1w + i * 2048, se1b + i * 16,
            se2w + i * 2048, se2b + i * 128, s2b);

        if (i == 0)
            fuse_kernel<false><<<1024, 256, 0, stream>>>(
                out3, s2b, x, 614400, nullptr, obn, fbn, 0, spOut, pooled);
        else
            fuse_kernel<true><<<1024, 256, 0, stream>>>(
                out3, s2b, spIn, 76800, x + i * 76800,
                obn + i * 512, fbn, i * 128, spOut, pooled);
    }

    logits_kernel<<<1, 256, 0, stream>>>(pooled, fcw, fcb, (float*)d_out);
}

// Round 4
// 1137.213 us; speedup vs baseline: 2.8669x; 1.4315x over previous
//
#include <hip/hip_runtime.h>
#include <hip/hip_bf16.h>

// Problem constants
#define B_ 32
#define T_ 600

typedef __attribute__((ext_vector_type(8))) short short8;
typedef __attribute__((ext_vector_type(4))) float f32x4;
typedef __attribute__((ext_vector_type(4))) unsigned short ushort4v;

static __device__ __forceinline__ unsigned short f2bf(float f) {
    unsigned u = __float_as_uint(f);
    u += 0x7FFFu + ((u >> 16) & 1u);
    return (unsigned short)(u >> 16);
}
static __device__ __forceinline__ float bf2f(unsigned short u) {
    return __uint_as_float(((unsigned)u) << 16);
}

// ---------------------------------------------------------------------------
// Fused 1x1-conv GEMM via bf16 MFMA: out[b,o,t] = bn(relu(W @ in + bias)).
// Optionally zeroes a 4096-float buffer (SE accumulator) and accumulates
// per-(b,o) time-sums for SE.
template<bool HAS_IN2, bool DO_SSUM>
__global__ __launch_bounds__(256) void gemm_kernel(
    const float* __restrict__ in0, int s0,
    const float* __restrict__ in1,            // b-stride 614400 (x slice)
    const float* __restrict__ Wg, const float* __restrict__ bias,
    const float* __restrict__ bnp, float* __restrict__ out,
    float* __restrict__ ssum,
    float* __restrict__ zbuf4096)
{
    __shared__ unsigned short Al[128][136];   // W[o][c] bf16, +8 pad
    __shared__ unsigned short Bl[64][136];    // in^T [t][c] bf16, +8 pad
    const int tid = threadIdx.x;
    const int b = blockIdx.y;
    const int t0 = blockIdx.x * 64;

    if (zbuf4096 != nullptr) {
        int fid = (b * gridDim.x + blockIdx.x) * 256 + tid;
        if (fid < 4096) zbuf4096[fid] = 0.f;
    }

    // stage A: 128x128 f32 weights -> bf16 LDS
    for (int e = tid; e < 128 * 32; e += 256) {
        int row = e >> 5, c4 = (e & 31) * 4;
        float4 w4 = *(const float4*)&Wg[row * 128 + c4];
        ushort4v u;
        u.x = f2bf(w4.x); u.y = f2bf(w4.y); u.z = f2bf(w4.z); u.w = f2bf(w4.w);
        *(ushort4v*)&Al[row][c4] = u;
    }
    // stage B: in[b, c, t0+t] (+in1) -> Bl[t][c] bf16 (transpose in LDS)
    {
        int t = tid & 63, cb = tid >> 6;
        int gt = t0 + t;
        bool inr = gt < T_;
        const float* p0 = in0 + b * s0 + gt;
        const float* p1 = HAS_IN2 ? (in1 + b * 614400 + gt) : nullptr;
        for (int q = 0; q < 32; q += 8) {
            unsigned short u8[8];
#pragma unroll
            for (int r = 0; r < 8; ++r) {
                int c = cb * 32 + q + r;
                float v = 0.f;
                if (inr) {
                    v = p0[c * T_];
                    if (HAS_IN2) v += p1[c * T_];
                }
                u8[r] = f2bf(v);
            }
            *(short8*)&Bl[t][cb * 32 + q] = *(short8*)u8;
        }
    }
    __syncthreads();

    const int wave = tid >> 6, lane = tid & 63;
    const int mBase = (wave >> 1) * 64, nBase = (wave & 1) * 32;
    const int lr = lane & 15, lq = lane >> 4;

    f32x4 acc[4][2];
#pragma unroll
    for (int mf = 0; mf < 4; ++mf)
#pragma unroll
        for (int nf = 0; nf < 2; ++nf) acc[mf][nf] = {0.f, 0.f, 0.f, 0.f};

#pragma unroll
    for (int kb = 0; kb < 4; ++kb) {
        short8 af[4], bfr[2];
#pragma unroll
        for (int mf = 0; mf < 4; ++mf)
            af[mf] = *(const short8*)&Al[mBase + mf * 16 + lr][kb * 32 + lq * 8];
#pragma unroll
        for (int nf = 0; nf < 2; ++nf)
            bfr[nf] = *(const short8*)&Bl[nBase + nf * 16 + lr][kb * 32 + lq * 8];
#pragma unroll
        for (int mf = 0; mf < 4; ++mf)
#pragma unroll
            for (int nf = 0; nf < 2; ++nf)
                acc[mf][nf] = __builtin_amdgcn_mfma_f32_16x16x32_bf16(
                    af[mf], bfr[nf], acc[mf][nf], 0, 0, 0);
    }

    // epilogue: bias -> relu -> bn -> store (+ optional SE partial time-sum)
#pragma unroll
    for (int mf = 0; mf < 4; ++mf) {
#pragma unroll
        for (int i = 0; i < 4; ++i) {
            int o = mBase + mf * 16 + lq * 4 + i;
            float g = bnp[o], be = bnp[128 + o], m = bnp[256 + o], vv = bnp[384 + o];
            float sc = g * rsqrtf(vv + 1e-5f), sh = be - m * sc;
            float bs = bias[o];
            float psum = 0.f;
#pragma unroll
            for (int nf = 0; nf < 2; ++nf) {
                int t = t0 + nBase + nf * 16 + lr;
                float v = fmaxf(acc[mf][nf][i] + bs, 0.f) * sc + sh;
                if (t < T_) { out[(b * 128 + o) * T_ + t] = v; psum += v; }
            }
            if (DO_SSUM) {
                psum += __shfl_xor(psum, 1);
                psum += __shfl_xor(psum, 2);
                psum += __shfl_xor(psum, 4);
                psum += __shfl_xor(psum, 8);
                if (lr == 0) atomicAdd(&ssum[b * 128 + o], psum);
            }
        }
    }
}

// ---------------------------------------------------------------------------
// Inner Res2 chain, per-slice-chain parallel, NO global atomics.
// Chain c: c==0 -> out1 ch112..127 (convs 0..6); c>=1 -> out1 ch 16(c-1)..
// (convs (c-1)..6). Each wg: one (b, t-tile, chain). Per conv step the new
// state's central TI columns are stored (bf16) to chainout[pair(j,c)].
constexpr int TI = 100;     // 600 = 6 * 100 (exact)
constexpr int ROWL = 134;   // >= 128 + slack

__global__ __launch_bounds__(128, 2) void inner_kernel(
    const float* __restrict__ out1, float* __restrict__ mid,
    unsigned short* __restrict__ chainout,
    const float* __restrict__ cwB, const float* __restrict__ cbB,
    const float* __restrict__ ibnB)
{
    __shared__ float st[2][16][ROWL];
    const int tid = threadIdx.x;
    const int tile = blockIdx.x;   // 0..5
    const int c = blockIdx.y;      // chain 0..7
    const int b = blockIdx.z;

    const int j0 = (c <= 1) ? 0 : (c - 1);
    const int nconv = 7 - j0;
    const int halo = 2 * nconv;
    const int X = TI + 2 * halo;   // <= 128
    const int ch0 = (c == 0) ? 112 : 16 * (c - 1);
    const int t0g = tile * TI - halo;

    // load initial state (zero outside [0,T)); chain 0 also copies its
    // central region to mid ch 112..127 (plain store, sole writer).
    for (int e = tid; e < 16 * X; e += 128) {
        int i = e / X, t = e - i * X;
        int g = t0g + t;
        float v = ((unsigned)g < T_) ? out1[(b * 128 + ch0 + i) * T_ + g] : 0.f;
        st[0][i][t] = v;
        if (c == 0 && t >= halo && t < halo + TI)
            mid[(b * 128 + 112 + i) * T_ + g] = v;
    }
    __syncthreads();

    const int op = tid & 7, tg = tid >> 3;   // 8 ch-pairs x 16 t-groups
    int cur = 0;
    for (int j = j0; j < 7; ++j) {
        const int k = j - j0;
        const int olo = 2 * k + 2, ohi = X - 2 * k - 2;

        float wA[16][3], wB[16][3];
        const float* wbase = &cwB[(j * 16 + op) * 48];
        const float* wbase2 = wbase + 8 * 48;
#pragma unroll
        for (int i = 0; i < 16; ++i)
#pragma unroll
            for (int kk = 0; kk < 3; ++kk) {
                wA[i][kk] = wbase[i * 3 + kk];
                wB[i][kk] = wbase2[i * 3 + kk];
            }
        const float biasA = cbB[j * 16 + op], biasB = cbB[j * 16 + op + 8];
        float gA = ibnB[(j * 4 + 0) * 16 + op], bA = ibnB[(j * 4 + 1) * 16 + op];
        float mA = ibnB[(j * 4 + 2) * 16 + op], vA = ibnB[(j * 4 + 3) * 16 + op];
        float gB = ibnB[(j * 4 + 0) * 16 + op + 8], bB = ibnB[(j * 4 + 1) * 16 + op + 8];
        float mB = ibnB[(j * 4 + 2) * 16 + op + 8], vB = ibnB[(j * 4 + 3) * 16 + op + 8];
        float iscA = gA * rsqrtf(vA + 1e-5f), ishA = bA - mA * iscA;
        float iscB = gB * rsqrtf(vB + 1e-5f), ishB = bB - mB * iscB;

        const int t8 = olo + tg * 8;
        const int nxt = cur ^ 1;
        if (t8 < ohi) {
            float accA[8], accB[8];
#pragma unroll
            for (int d = 0; d < 8; ++d) { accA[d] = biasA; accB[d] = biasB; }
#pragma unroll
            for (int i = 0; i < 16; ++i) {
                const float* row = &st[cur][i][0];
                float v[12];
#pragma unroll
                for (int m = 0; m < 6; ++m) {
                    float2 r2 = *(const float2*)&row[t8 - 2 + 2 * m];
                    v[2 * m] = r2.x; v[2 * m + 1] = r2.y;
                }
#pragma unroll
                for (int d = 0; d < 8; ++d) {
                    accA[d] += wA[i][0] * v[d] + wA[i][1] * v[d + 2] + wA[i][2] * v[d + 4];
                    accB[d] += wB[i][0] * v[d] + wB[i][1] * v[d + 2] + wB[i][2] * v[d + 4];
                }
            }
#pragma unroll
            for (int d = 0; d < 8; ++d) {
                int t = t8 + d;
                int g = t0g + t;
                bool ok = (t < ohi) && ((unsigned)g < T_);
                float va = ok ? fmaxf(accA[d], 0.f) * iscA + ishA : 0.f;
                float vb = ok ? fmaxf(accB[d], 0.f) * iscB + ishB : 0.f;
                st[nxt][op][t] = va;
                st[nxt][op + 8][t] = vb;
            }
        }
        __syncthreads();
        cur = nxt;

        // store central region of the new state to chainout (bf16, coalesced)
        {
            const int pair = j * (j + 3) / 2 + c;
            unsigned short* dst = chainout + ((size_t)(pair * B_ + b) * 16) * T_
                                + tile * TI;
            for (int e = tid; e < 16 * TI; e += 128) {
                int i = e / TI, tt = e - i * TI;
                dst[i * T_ + tt] = f2bf(st[cur][i][halo + tt]);
            }
        }
    }
}

// ---------------------------------------------------------------------------
// Weighted scale-sum: mid[b,16j+i,t] = sum_s ws_j[s] * chainout[pair0+s][b,i,t]
// Flat vectorized: one thread per 8-wide t-vector (600 = 75*8).
constexpr int WSUM_ITEMS = 7 * B_ * 16 * 75;   // 268800

__global__ __launch_bounds__(256) void wsum_kernel(
    const unsigned short* __restrict__ chainout, float* __restrict__ mid,
    const float* __restrict__ ws0, const float* __restrict__ ws1,
    const float* __restrict__ ws2, const float* __restrict__ ws3,
    const float* __restrict__ ws4, const float* __restrict__ ws5,
    const float* __restrict__ ws6)
{
    int e = blockIdx.x * 256 + threadIdx.x;
    if (e >= WSUM_ITEMS) return;
    const int j = e / (B_ * 16 * 75);
    int r = e - j * (B_ * 16 * 75);
    const int b = r / (16 * 75);
    r -= b * (16 * 75);
    const int i = r / 75;
    const int tv = r - i * 75;

    const float* wp;
    switch (j) {
        case 0: wp = ws0; break; case 1: wp = ws1; break;
        case 2: wp = ws2; break; case 3: wp = ws3; break;
        case 4: wp = ws4; break; case 5: wp = ws5; break;
        default: wp = ws6; break;
    }
    const int nsl = j + 2, pair0 = j * (j + 3) / 2;
    const unsigned short* src = chainout + (size_t)(pair0 * B_ + b) * 9600
                              + i * T_ + tv * 8;
    float acc[8] = {0.f, 0.f, 0.f, 0.f, 0.f, 0.f, 0.f, 0.f};
    for (int s = 0; s < nsl; ++s) {
        short8 v = *(const short8*)(src + (size_t)s * B_ * 9600);
        float w = wp[s];
#pragma unroll
        for (int d = 0; d < 8; ++d)
            acc[d] += w * bf2f((unsigned short)v[d]);
    }
    float* dst = mid + (size_t)(b * 128 + 16 * j + i) * T_ + tv * 8;
    *(f32x4*)dst = {acc[0], acc[1], acc[2], acc[3]};
    *(f32x4*)(dst + 4) = {acc[4], acc[5], acc[6], acc[7]};
}

// ---------------------------------------------------------------------------
// SE excitation: s2 = sigmoid(W2 relu(W1 (ssum/T) + b1) + b2)
__global__ __launch_bounds__(128) void se_kernel(
    const float* __restrict__ ssum, const float* __restrict__ w1se,
    const float* __restrict__ b1se, const float* __restrict__ w2se,
    const float* __restrict__ b2se, float* __restrict__ s2b)
{
    __shared__ float sL[128], hL[16];
    const int tid = threadIdx.x, b = blockIdx.x;
    sL[tid] = ssum[b * 128 + tid] * (1.f / 600.f);
    __syncthreads();
    if (tid < 16) {
        float a = b1se[tid];
        for (int c = 0; c < 128; ++c) a += w1se[tid * 128 + c] * sL[c];
        hL[tid] = fmaxf(a, 0.f);
    }
    __syncthreads();
    float a = b2se[tid];
#pragma unroll
    for (int q = 0; q < 16; ++q) a += w2se[tid * 16 + q] * hL[q];
    s2b[b * 128 + tid] = 1.f / (1.f + expf(-a));
}

// ---------------------------------------------------------------------------
// Elementwise tail: y = out3*s2 + residual; sp = obn(relu(y)); store sp;
// pooled[b, chOff+c] = mean_t relu(fbn(sp)).
template<bool HAS_R2>
__global__ __launch_bounds__(256) void fuse_kernel(
    const float* __restrict__ out3, const float* __restrict__ s2b,
    const float* __restrict__ res0, int r0s,
    const float* __restrict__ res1,
    const float* __restrict__ obnp, const float* __restrict__ fbnp, int chOff,
    float* __restrict__ spOut, float* __restrict__ pooled)
{
    const int tid = threadIdx.x;
    const int row = blockIdx.x * 4 + (tid >> 6);
    const int lane = tid & 63;
    const int b = row >> 7, c = row & 127;
    const float s2v = s2b[b * 128 + c];
    float g = obnp[c], bb = obnp[128 + c], m = obnp[256 + c], v = obnp[384 + c];
    float osc = g * rsqrtf(v + 1e-5f), osh = bb - m * osc;
    int fc = chOff + c;
    float fg = fbnp[fc], fb2 = fbnp[1024 + fc], fm = fbnp[2048 + fc], fv = fbnp[3072 + fc];
    float fsc = fg * rsqrtf(fv + 1e-5f), fsh = fb2 - fm * fsc;
    int base = (b * 128 + c) * T_;
    float psum = 0.f;
    for (int t = lane; t < T_; t += 64) {
        float o3 = out3[base + t];
        float r = res0[b * r0s + c * T_ + t];
        if (HAS_R2) r += res1[b * 614400 + c * T_ + t];
        float fin = o3 * s2v + r;
        float sp = fmaxf(fin, 0.f) * osc + osh;
        spOut[base + t] = sp;
        psum += fmaxf(sp * fsc + fsh, 0.f);
    }
    for (int mo = 32; mo > 0; mo >>= 1) psum += __shfl_xor(psum, mo);
    if (lane == 0) pooled[b * 1024 + fc] = psum * (1.f / 600.f);
}

// pooled tail for x channels 896..1023
__global__ __launch_bounds__(256) void pooledx_kernel(
    const float* __restrict__ x, const float* __restrict__ fbnp,
    float* __restrict__ pooled)
{
    const int tid = threadIdx.x;
    const int row = blockIdx.x * 4 + (tid >> 6);
    const int lane = tid & 63;
    const int b = row >> 7, c = row & 127;
    int fc = 896 + c;
    float fg = fbnp[fc], fb2 = fbnp[1024 + fc], fm = fbnp[2048 + fc], fv = fbnp[3072 + fc];
    float fsc = fg * rsqrtf(fv + 1e-5f), fsh = fb2 - fm * fsc;
    int base = (b * 1024 + fc) * T_;
    float psum = 0.f;
    for (int t = lane; t < T_; t += 64)
        psum += fmaxf(x[base + t] * fsc + fsh, 0.f);
    for (int mo = 32; mo > 0; mo >>= 1) psum += __shfl_xor(psum, mo);
    if (lane == 0) pooled[b * 1024 + fc] = psum * (1.f / 600.f);
}

// final classifier
__global__ __launch_bounds__(256) void logits_kernel(
    const float* __restrict__ pooled, const float* __restrict__ fcw,
    const float* __restrict__ fcb, float* __restrict__ outp)
{
    __shared__ float red[256];
    const int tid = threadIdx.x;
    const int item = tid & 63, part = tid >> 6;
    const int b = item >> 1, cls = item & 1;
    float a = 0.f;
    for (int c = part * 256; c < part * 256 + 256; ++c)
        a += pooled[b * 1024 + c] * fcw[cls * 1024 + c];
    red[tid] = a;
    __syncthreads();
    if (tid < 64)
        outp[b * 2 + cls] = red[tid] + red[tid + 64] + red[tid + 128] + red[tid + 192] + fcb[cls];
}

// ---------------------------------------------------------------------------
extern "C" void kernel_launch(void* const* d_in, const int* in_sizes, int n_in,
                              void* d_out, int out_size, void* d_ws, size_t ws_size,
                              hipStream_t stream) {
    const float* x    = (const float*)d_in[0];
    const float* w1   = (const float*)d_in[1];
    const float* b1   = (const float*)d_in[2];
    const float* bn1  = (const float*)d_in[3];
    const float* cw   = (const float*)d_in[4];
    const float* cb   = (const float*)d_in[5];
    const float* ibn  = (const float*)d_in[6];
    const float* w3   = (const float*)d_in[7];
    const float* b3   = (const float*)d_in[8];
    const float* bn3  = (const float*)d_in[9];
    const float* se1w = (const float*)d_in[10];
    const float* se1b = (const float*)d_in[11];
    const float* se2w = (const float*)d_in[12];
    const float* se2b = (const float*)d_in[13];
    const float* obn  = (const float*)d_in[14];
    const float* fbn  = (const float*)d_in[15];
    const float* fcw  = (const float*)d_in[16];
    const float* fcb  = (const float*)d_in[17];
    const float* wsp[7] = {(const float*)d_in[18], (const float*)d_in[19],
                           (const float*)d_in[20], (const float*)d_in[21],
                           (const float*)d_in[22], (const float*)d_in[23],
                           (const float*)d_in[24]};

    float* ws = (float*)d_ws;
    const int NT = 128 * T_ * B_;          // 2,457,600 floats per (B,128,T)
    float* out1   = ws;
    float* mid    = out1 + NT;
    float* out3   = mid + NT;
    float* spA    = out3 + NT;
    float* spB    = spA + NT;
    float* sbuf   = spB + NT;              // 7*4096
    float* s2b    = sbuf + 7 * 4096;       // 4096
    float* pooled = s2b + 4096;            // 32768
    unsigned short* chainout = (unsigned short*)(pooled + 32768); // 35*32*9600 ushort

    pooledx_kernel<<<1024, 256, 0, stream>>>(x, fbn, pooled);

    dim3 gGrid(10, B_);        // ceil(600/64) x B
    dim3 iGrid(6, 8, B_);      // t-tiles x chains x B
    const int wGrid = (WSUM_ITEMS + 255) / 256;   // 1050

    float* spBufs[2] = {spA, spB};
    for (int i = 0; i < 7; ++i) {
        float* spOut = spBufs[i & 1];
        const float* spIn = spBufs[(i & 1) ^ 1];

        // gemm1 also zeroes this block's SE accumulator
        if (i == 0)
            gemm_kernel<false, false><<<gGrid, 256, 0, stream>>>(
                x, 614400, nullptr, w1, b1, bn1, out1, nullptr,
                sbuf + i * 4096);
        else
            gemm_kernel<true, false><<<gGrid, 256, 0, stream>>>(
                spIn, 76800, x + i * 76800,
                w1 + i * 16384, b1 + i * 128, bn1 + i * 512, out1, nullptr,
                sbuf + i * 4096);

        inner_kernel<<<iGrid, 128, 0, stream>>>(
            out1, mid, chainout, cw + i * 5376, cb + i * 112, ibn + i * 448);

        wsum_kernel<<<wGrid, 256, 0, stream>>>(
            chainout, mid,
            wsp[0] + 2 * i, wsp[1] + 3 * i, wsp[2] + 4 * i, wsp[3] + 5 * i,
            wsp[4] + 6 * i, wsp[5] + 7 * i, wsp[6] + 8 * i);

        gemm_kernel<false, true><<<gGrid, 256, 0, stream>>>(
            mid, 76800, nullptr,
            w3 + i * 16384, b3 + i * 128, bn3 + i * 512, out3, sbuf + i * 4096,
            nullptr);

        se_kernel<<<B_, 128, 0, stream>>>(
            sbuf + i * 4096, se1w + i * 2048, se1b + i * 16,
            se2w + i * 2048, se2b + i * 128, s2b);

        if (i == 0)
            fuse_kernel<false><<<1024, 256, 0, stream>>>(
                out3, s2b, x, 614400, nullptr, obn, fbn, 0, spOut, pooled);
        else
            fuse_kernel<true><<<1024, 256, 0, stream>>>(
                out3, s2b, spIn, 76800, x + i * 76800,
                obn + i * 512, fbn, i * 128, spOut, pooled);
    }

    logits_kernel<<<1, 256, 0, stream>>>(pooled, fcw, fcb, (float*)d_out);
}

// Round 5
// 912.248 us; speedup vs baseline: 3.5739x; 1.2466x over previous
//
#include <hip/hip_runtime.h>
#include <hip/hip_bf16.h>

// Problem constants
#define B_ 32
#define T_ 600

typedef __attribute__((ext_vector_type(8))) short short8;
typedef __attribute__((ext_vector_type(4))) float f32x4;
typedef __attribute__((ext_vector_type(4))) unsigned short ushort4v;

static __device__ __forceinline__ unsigned short f2bf(float f) {
    unsigned u = __float_as_uint(f);
    u += 0x7FFFu + ((u >> 16) & 1u);
    return (unsigned short)(u >> 16);
}
static __device__ __forceinline__ float bf2f(unsigned short u) {
    return __uint_as_float(((unsigned)u) << 16);
}

// ---------------------------------------------------------------------------
// Fused 1x1-conv GEMM via bf16 MFMA: out[b,o,t] = bn(relu(W @ in + bias)).
// OUT_BF16: store output as bf16 (for inner_kernel consumption).
// DO_SSUM: accumulate per-(b,o) time-sums for SE. Optionally zero 4096 floats.
template<bool HAS_IN2, bool DO_SSUM, bool OUT_BF16>
__global__ __launch_bounds__(256) void gemm_kernel(
    const float* __restrict__ in0, int s0,
    const float* __restrict__ in1,            // b-stride 614400 (x slice)
    const float* __restrict__ Wg, const float* __restrict__ bias,
    const float* __restrict__ bnp, void* __restrict__ outv,
    float* __restrict__ ssum,
    float* __restrict__ zbuf4096)
{
    __shared__ unsigned short Al[128][136];   // W[o][c] bf16, +8 pad
    __shared__ unsigned short Bl[64][136];    // in^T [t][c] bf16, +8 pad
    const int tid = threadIdx.x;
    const int b = blockIdx.y;
    const int t0 = blockIdx.x * 64;

    if (zbuf4096 != nullptr) {
        int fid = (b * gridDim.x + blockIdx.x) * 256 + tid;
        if (fid < 4096) zbuf4096[fid] = 0.f;
    }

    // stage A: 128x128 f32 weights -> bf16 LDS
    for (int e = tid; e < 128 * 32; e += 256) {
        int row = e >> 5, c4 = (e & 31) * 4;
        float4 w4 = *(const float4*)&Wg[row * 128 + c4];
        ushort4v u;
        u.x = f2bf(w4.x); u.y = f2bf(w4.y); u.z = f2bf(w4.z); u.w = f2bf(w4.w);
        *(ushort4v*)&Al[row][c4] = u;
    }
    // stage B: in[b, c, t0+t] (+in1) -> Bl[t][c] bf16 (transpose in LDS)
    {
        int t = tid & 63, cb = tid >> 6;
        int gt = t0 + t;
        bool inr = gt < T_;
        const float* p0 = in0 + b * s0 + gt;
        const float* p1 = HAS_IN2 ? (in1 + b * 614400 + gt) : nullptr;
        for (int q = 0; q < 32; q += 8) {
            unsigned short u8[8];
#pragma unroll
            for (int r = 0; r < 8; ++r) {
                int c = cb * 32 + q + r;
                float v = 0.f;
                if (inr) {
                    v = p0[c * T_];
                    if (HAS_IN2) v += p1[c * T_];
                }
                u8[r] = f2bf(v);
            }
            *(short8*)&Bl[t][cb * 32 + q] = *(short8*)u8;
        }
    }
    __syncthreads();

    const int wave = tid >> 6, lane = tid & 63;
    const int mBase = (wave >> 1) * 64, nBase = (wave & 1) * 32;
    const int lr = lane & 15, lq = lane >> 4;

    f32x4 acc[4][2];
#pragma unroll
    for (int mf = 0; mf < 4; ++mf)
#pragma unroll
        for (int nf = 0; nf < 2; ++nf) acc[mf][nf] = {0.f, 0.f, 0.f, 0.f};

#pragma unroll
    for (int kb = 0; kb < 4; ++kb) {
        short8 af[4], bfr[2];
#pragma unroll
        for (int mf = 0; mf < 4; ++mf)
            af[mf] = *(const short8*)&Al[mBase + mf * 16 + lr][kb * 32 + lq * 8];
#pragma unroll
        for (int nf = 0; nf < 2; ++nf)
            bfr[nf] = *(const short8*)&Bl[nBase + nf * 16 + lr][kb * 32 + lq * 8];
#pragma unroll
        for (int mf = 0; mf < 4; ++mf)
#pragma unroll
            for (int nf = 0; nf < 2; ++nf)
                acc[mf][nf] = __builtin_amdgcn_mfma_f32_16x16x32_bf16(
                    af[mf], bfr[nf], acc[mf][nf], 0, 0, 0);
    }

    // epilogue: bias -> relu -> bn -> store (+ optional SE partial time-sum)
#pragma unroll
    for (int mf = 0; mf < 4; ++mf) {
#pragma unroll
        for (int i = 0; i < 4; ++i) {
            int o = mBase + mf * 16 + lq * 4 + i;
            float g = bnp[o], be = bnp[128 + o], m = bnp[256 + o], vv = bnp[384 + o];
            float sc = g * rsqrtf(vv + 1e-5f), sh = be - m * sc;
            float bs = bias[o];
            float psum = 0.f;
#pragma unroll
            for (int nf = 0; nf < 2; ++nf) {
                int t = t0 + nBase + nf * 16 + lr;
                float v = fmaxf(acc[mf][nf][i] + bs, 0.f) * sc + sh;
                if (t < T_) {
                    if (OUT_BF16)
                        ((unsigned short*)outv)[(b * 128 + o) * T_ + t] = f2bf(v);
                    else
                        ((float*)outv)[(b * 128 + o) * T_ + t] = v;
                    psum += v;
                }
            }
            if (DO_SSUM) {
                psum += __shfl_xor(psum, 1);
                psum += __shfl_xor(psum, 2);
                psum += __shfl_xor(psum, 4);
                psum += __shfl_xor(psum, 8);
                if (lr == 0) atomicAdd(&ssum[b * 128 + o], psum);
            }
        }
    }
}

// ---------------------------------------------------------------------------
// Inner Res2 chain via MFMA. One wg per (t-tile, chain, b); state bf16 in LDS
// [row = t+2][16 ch], row stride 24 ushorts (48B, 16B-aligned, low-conflict).
// Conv step = 2x mfma_f32_16x16x32_bf16 per 16-t tile:
//   MFMA#1: K=32 = taps{-2,0} x 16ch ; MFMA#2: K=32 = tap{+2} x 16ch + zeros.
constexpr int TI = 100;     // 600 = 6 * 100 (exact)
constexpr int NROW = 132;   // rows: t+2 for t in [-2, 130)
constexpr int RS = 24;      // row stride in ushorts (48 bytes)

__global__ __launch_bounds__(128, 3) void inner_kernel(
    const unsigned short* __restrict__ out1, float* __restrict__ mid,
    unsigned short* __restrict__ chainout,
    const float* __restrict__ cwB, const float* __restrict__ cbB,
    const float* __restrict__ ibnB)
{
    __shared__ __attribute__((aligned(16))) unsigned short st[2][NROW][RS];
    __shared__ __attribute__((aligned(16))) unsigned short wL1[7 * 16 * 32];
    __shared__ __attribute__((aligned(16))) unsigned short wL2[7 * 16 * 16];
    __shared__ __attribute__((aligned(16))) unsigned short zb[16];
    __shared__ __attribute__((aligned(16))) float pL[7 * 16][4];

    const int tid = threadIdx.x;
    const int tile = blockIdx.x;   // 0..5
    const int c = blockIdx.y;      // chain 0..7
    const int b = blockIdx.z;

    const int j0 = (c <= 1) ? 0 : (c - 1);
    const int nconv = 7 - j0;
    const int halo = 2 * nconv;
    const int X = TI + 2 * halo;   // <= 128
    const int ch0 = (c == 0) ? 112 : 16 * (c - 1);
    const int t0g = tile * TI - halo;

    // zero both state buffers (vector writes); zero block for MFMA#2 upper K
    for (int e = tid; e < 2 * NROW * RS / 4; e += 128)
        ((ushort4v*)st)[e] = ushort4v{0, 0, 0, 0};
    if (tid < 16) zb[tid] = 0;

    // stage conv weights (bf16): wL1[k][o][tap*16+i] taps 0,1; wL2[k][o][i] tap 2
    for (int e = tid; e < nconv * 512; e += 128) {
        int k = e >> 9, rem = e & 511, o = rem >> 5, col = rem & 31;
        int tap = col >> 4, i = col & 15;
        wL1[e] = f2bf(cwB[((j0 + k) * 16 + o) * 48 + i * 3 + tap]);
    }
    for (int e = tid; e < nconv * 256; e += 128) {
        int k = e >> 8, rem = e & 255, o = rem >> 4, i = rem & 15;
        wL2[e] = f2bf(cwB[((j0 + k) * 16 + o) * 48 + i * 3 + 2]);
    }
    // per-(step, out-ch) params: {bias, bn_scale, bn_shift, 0}
    for (int e = tid; e < nconv * 16; e += 128) {
        int k = e >> 4, o = e & 15, j = j0 + k;
        float g = ibnB[(j * 4 + 0) * 16 + o], bb = ibnB[(j * 4 + 1) * 16 + o];
        float m = ibnB[(j * 4 + 2) * 16 + o], v = ibnB[(j * 4 + 3) * 16 + o];
        float sc = g * rsqrtf(v + 1e-5f);
        pL[e][0] = cbB[j * 16 + o];
        pL[e][1] = sc;
        pL[e][2] = bb - m * sc;
        pL[e][3] = 0.f;
    }
    __syncthreads();   // zero-init visible before state staging writes

    // stage initial state rows [2, X+2); chain 0 also copies central to mid
    {
        const int i = tid >> 3, ph = tid & 7;
        const unsigned short* src = out1 + (size_t)(b * 128 + ch0 + i) * T_;
        for (int t = ph; t < X; t += 8) {
            int g = t0g + t;
            unsigned short v = ((unsigned)g < (unsigned)T_) ? src[g] : (unsigned short)0;
            st[0][t + 2][i] = v;
            if (c == 0 && t >= halo && t < halo + TI)
                mid[(size_t)(b * 128 + 112 + i) * T_ + g] = bf2f(v);
        }
    }
    __syncthreads();

    const int lane = tid & 63, wave = tid >> 6;
    const int lt = lane & 15, q = lane >> 4;
    const int i0 = (q & 1) * 8;
    const int roff1 = (q < 2) ? 0 : 2;   // MFMA#1: taps at rows t / t+2

    int cur = 0;
    for (int k = 0; k < nconv; ++k) {
        const int olo = 2 * k + 2, ohi = X - 2 * k - 2;
        const int thi = (ohi + 15) >> 4;   // tiles to compute
        const int nxt = cur ^ 1;

        // A fragments (per step, uniform over tiles)
        short8 A1 = *(const short8*)&wL1[(k * 16 + lt) * 32 + q * 8];
        short8 A2 = (q < 2)
            ? *(const short8*)&wL2[(k * 16 + lt) * 16 + q * 8]
            : *(const short8*)&zb[i0];
        // epilogue params for this lane's 4 output channels (o = 4q + r)
        float4 pp[4];
#pragma unroll
        for (int r = 0; r < 4; ++r)
            pp[r] = *(const float4*)&pL[k * 16 + 4 * q + r][0];

        for (int tt = wave; tt < thi; tt += 2) {
            const int t = tt * 16 + lt;     // buffer t-coord (= C col)
            f32x4 acc = {0.f, 0.f, 0.f, 0.f};
            short8 B1 = *(const short8*)&st[cur][t + roff1][i0];
            acc = __builtin_amdgcn_mfma_f32_16x16x32_bf16(A1, B1, acc, 0, 0, 0);
            short8 B2 = *(const short8*)&st[cur][t + 4][i0];
            acc = __builtin_amdgcn_mfma_f32_16x16x32_bf16(A2, B2, acc, 0, 0, 0);

            const int g = t0g + t;
            const bool ok = (t >= olo) && (t < ohi) && ((unsigned)g < (unsigned)T_);
            ushort4v o4;
#pragma unroll
            for (int r = 0; r < 4; ++r) {
                float v = fmaxf(acc[r] + pp[r].x, 0.f) * pp[r].y + pp[r].z;
                unsigned short h = f2bf(v);
                o4[r] = ok ? h : (unsigned short)0;
            }
            *(ushort4v*)&st[nxt][t + 2][4 * q] = o4;
        }
        __syncthreads();

        // store central TI columns of new state to chainout (bf16)
        {
            const int j = j0 + k;
            const int pair = j * (j + 3) / 2 + c;
            unsigned short* dst = chainout + ((size_t)(pair * B_ + b) * 16) * T_
                                + tile * TI;
            const int i = tid >> 3, ph = tid & 7;
            for (int t2 = ph; t2 < TI; t2 += 8)
                dst[i * T_ + t2] = st[nxt][halo + t2 + 2][i];
        }
        cur = nxt;
    }
}

// ---------------------------------------------------------------------------
// Weighted scale-sum: mid[b,16j+i,t] = sum_s ws_j[s] * chainout[pair0+s][b,i,t]
constexpr int WSUM_ITEMS = 7 * B_ * 16 * 75;   // 268800

__global__ __launch_bounds__(256) void wsum_kernel(
    const unsigned short* __restrict__ chainout, float* __restrict__ mid,
    const float* __restrict__ ws0, const float* __restrict__ ws1,
    const float* __restrict__ ws2, const float* __restrict__ ws3,
    const float* __restrict__ ws4, const float* __restrict__ ws5,
    const float* __restrict__ ws6)
{
    int e = blockIdx.x * 256 + threadIdx.x;
    if (e >= WSUM_ITEMS) return;
    const int j = e / (B_ * 16 * 75);
    int r = e - j * (B_ * 16 * 75);
    const int b = r / (16 * 75);
    r -= b * (16 * 75);
    const int i = r / 75;
    const int tv = r - i * 75;

    const float* wp;
    switch (j) {
        case 0: wp = ws0; break; case 1: wp = ws1; break;
        case 2: wp = ws2; break; case 3: wp = ws3; break;
        case 4: wp = ws4; break; case 5: wp = ws5; break;
        default: wp = ws6; break;
    }
    const int nsl = j + 2, pair0 = j * (j + 3) / 2;
    const unsigned short* src = chainout + (size_t)(pair0 * B_ + b) * 9600
                              + i * T_ + tv * 8;
    float acc[8] = {0.f, 0.f, 0.f, 0.f, 0.f, 0.f, 0.f, 0.f};
    for (int s = 0; s < nsl; ++s) {
        short8 v = *(const short8*)(src + (size_t)s * B_ * 9600);
        float w = wp[s];
#pragma unroll
        for (int d = 0; d < 8; ++d)
            acc[d] += w * bf2f((unsigned short)v[d]);
    }
    float* dst = mid + (size_t)(b * 128 + 16 * j + i) * T_ + tv * 8;
    *(f32x4*)dst = {acc[0], acc[1], acc[2], acc[3]};
    *(f32x4*)(dst + 4) = {acc[4], acc[5], acc[6], acc[7]};
}

// ---------------------------------------------------------------------------
// SE excitation: s2 = sigmoid(W2 relu(W1 (ssum/T) + b1) + b2)
__global__ __launch_bounds__(128) void se_kernel(
    const float* __restrict__ ssum, const float* __restrict__ w1se,
    const float* __restrict__ b1se, const float* __restrict__ w2se,
    const float* __restrict__ b2se, float* __restrict__ s2b)
{
    __shared__ float sL[128], hL[16];
    const int tid = threadIdx.x, b = blockIdx.x;
    sL[tid] = ssum[b * 128 + tid] * (1.f / 600.f);
    __syncthreads();
    if (tid < 16) {
        float a = b1se[tid];
        for (int c = 0; c < 128; ++c) a += w1se[tid * 128 + c] * sL[c];
        hL[tid] = fmaxf(a, 0.f);
    }
    __syncthreads();
    float a = b2se[tid];
#pragma unroll
    for (int q = 0; q < 16; ++q) a += w2se[tid * 16 + q] * hL[q];
    s2b[b * 128 + tid] = 1.f / (1.f + expf(-a));
}

// ---------------------------------------------------------------------------
// Elementwise tail: y = out3*s2 + residual; sp = obn(relu(y)); store sp;
// pooled[b, chOff+c] = mean_t relu(fbn(sp)).
template<bool HAS_R2>
__global__ __launch_bounds__(256) void fuse_kernel(
    const float* __restrict__ out3, const float* __restrict__ s2b,
    const float* __restrict__ res0, int r0s,
    const float* __restrict__ res1,
    const float* __restrict__ obnp, const float* __restrict__ fbnp, int chOff,
    float* __restrict__ spOut, float* __restrict__ pooled)
{
    const int tid = threadIdx.x;
    const int row = blockIdx.x * 4 + (tid >> 6);
    const int lane = tid & 63;
    const int b = row >> 7, c = row & 127;
    const float s2v = s2b[b * 128 + c];
    float g = obnp[c], bb = obnp[128 + c], m = obnp[256 + c], v = obnp[384 + c];
    float osc = g * rsqrtf(v + 1e-5f), osh = bb - m * osc;
    int fc = chOff + c;
    float fg = fbnp[fc], fb2 = fbnp[1024 + fc], fm = fbnp[2048 + fc], fv = fbnp[3072 + fc];
    float fsc = fg * rsqrtf(fv + 1e-5f), fsh = fb2 - fm * fsc;
    int base = (b * 128 + c) * T_;
    float psum = 0.f;
    for (int t = lane; t < T_; t += 64) {
        float o3 = out3[base + t];
        float r = res0[b * r0s + c * T_ + t];
        if (HAS_R2) r += res1[b * 614400 + c * T_ + t];
        float fin = o3 * s2v + r;
        float sp = fmaxf(fin, 0.f) * osc + osh;
        spOut[base + t] = sp;
        psum += fmaxf(sp * fsc + fsh, 0.f);
    }
    for (int mo = 32; mo > 0; mo >>= 1) psum += __shfl_xor(psum, mo);
    if (lane == 0) pooled[b * 1024 + fc] = psum * (1.f / 600.f);
}

// pooled tail for x channels 896..1023
__global__ __launch_bounds__(256) void pooledx_kernel(
    const float* __restrict__ x, const float* __restrict__ fbnp,
    float* __restrict__ pooled)
{
    const int tid = threadIdx.x;
    const int row = blockIdx.x * 4 + (tid >> 6);
    const int lane = tid & 63;
    const int b = row >> 7, c = row & 127;
    int fc = 896 + c;
    float fg = fbnp[fc], fb2 = fbnp[1024 + fc], fm = fbnp[2048 + fc], fv = fbnp[3072 + fc];
    float fsc = fg * rsqrtf(fv + 1e-5f), fsh = fb2 - fm * fsc;
    int base = (b * 1024 + fc) * T_;
    float psum = 0.f;
    for (int t = lane; t < T_; t += 64)
        psum += fmaxf(x[base + t] * fsc + fsh, 0.f);
    for (int mo = 32; mo > 0; mo >>= 1) psum += __shfl_xor(psum, mo);
    if (lane == 0) pooled[b * 1024 + fc] = psum * (1.f / 600.f);
}

// final classifier
__global__ __launch_bounds__(256) void logits_kernel(
    const float* __restrict__ pooled, const float* __restrict__ fcw,
    const float* __restrict__ fcb, float* __restrict__ outp)
{
    __shared__ float red[256];
    const int tid = threadIdx.x;
    const int item = tid & 63, part = tid >> 6;
    const int b = item >> 1, cls = item & 1;
    float a = 0.f;
    for (int c = part * 256; c < part * 256 + 256; ++c)
        a += pooled[b * 1024 + c] * fcw[cls * 1024 + c];
    red[tid] = a;
    __syncthreads();
    if (tid < 64)
        outp[b * 2 + cls] = red[tid] + red[tid + 64] + red[tid + 128] + red[tid + 192] + fcb[cls];
}

// ---------------------------------------------------------------------------
extern "C" void kernel_launch(void* const* d_in, const int* in_sizes, int n_in,
                              void* d_out, int out_size, void* d_ws, size_t ws_size,
                              hipStream_t stream) {
    const float* x    = (const float*)d_in[0];
    const float* w1   = (const float*)d_in[1];
    const float* b1   = (const float*)d_in[2];
    const float* bn1  = (const float*)d_in[3];
    const float* cw   = (const float*)d_in[4];
    const float* cb   = (const float*)d_in[5];
    const float* ibn  = (const float*)d_in[6];
    const float* w3   = (const float*)d_in[7];
    const float* b3   = (const float*)d_in[8];
    const float* bn3  = (const float*)d_in[9];
    const float* se1w = (const float*)d_in[10];
    const float* se1b = (const float*)d_in[11];
    const float* se2w = (const float*)d_in[12];
    const float* se2b = (const float*)d_in[13];
    const float* obn  = (const float*)d_in[14];
    const float* fbn  = (const float*)d_in[15];
    const float* fcw  = (const float*)d_in[16];
    const float* fcb  = (const float*)d_in[17];
    const float* wsp[7] = {(const float*)d_in[18], (const float*)d_in[19],
                           (const float*)d_in[20], (const float*)d_in[21],
                           (const float*)d_in[22], (const float*)d_in[23],
                           (const float*)d_in[24]};

    float* ws = (float*)d_ws;
    const int NT = 128 * T_ * B_;          // 2,457,600 per (B,128,T) tensor
    unsigned short* out1h = (unsigned short*)ws;   // bf16, fits in NT floats
    float* mid    = ws + NT;
    float* out3   = mid + NT;
    float* spA    = out3 + NT;
    float* spB    = spA + NT;
    float* sbuf   = spB + NT;              // 7*4096
    float* s2b    = sbuf + 7 * 4096;       // 4096
    float* pooled = s2b + 4096;            // 32768
    unsigned short* chainout = (unsigned short*)(pooled + 32768); // 35*32*9600 ushort

    pooledx_kernel<<<1024, 256, 0, stream>>>(x, fbn, pooled);

    dim3 gGrid(10, B_);        // ceil(600/64) x B
    dim3 iGrid(6, 8, B_);      // t-tiles x chains x B
    const int wGrid = (WSUM_ITEMS + 255) / 256;   // 1050

    float* spBufs[2] = {spA, spB};
    for (int i = 0; i < 7; ++i) {
        float* spOut = spBufs[i & 1];
        const float* spIn = spBufs[(i & 1) ^ 1];

        // gemm1 (bf16 output) also zeroes this block's SE accumulator
        if (i == 0)
            gemm_kernel<false, false, true><<<gGrid, 256, 0, stream>>>(
                x, 614400, nullptr, w1, b1, bn1, out1h, nullptr,
                sbuf + i * 4096);
        else
            gemm_kernel<true, false, true><<<gGrid, 256, 0, stream>>>(
                spIn, 76800, x + i * 76800,
                w1 + i * 16384, b1 + i * 128, bn1 + i * 512, out1h, nullptr,
                sbuf + i * 4096);

        inner_kernel<<<iGrid, 128, 0, stream>>>(
            out1h, mid, chainout, cw + i * 5376, cb + i * 112, ibn + i * 448);

        wsum_kernel<<<wGrid, 256, 0, stream>>>(
            chainout, mid,
            wsp[0] + 2 * i, wsp[1] + 3 * i, wsp[2] + 4 * i, wsp[3] + 5 * i,
            wsp[4] + 6 * i, wsp[5] + 7 * i, wsp[6] + 8 * i);

        gemm_kernel<false, true, false><<<gGrid, 256, 0, stream>>>(
            mid, 76800, nullptr,
            w3 + i * 16384, b3 + i * 128, bn3 + i * 512, out3, sbuf + i * 4096,
            nullptr);

        se_kernel<<<B_, 128, 0, stream>>>(
            sbuf + i * 4096, se1w + i * 2048, se1b + i * 16,
            se2w + i * 2048, se2b + i * 128, s2b);

        if (i == 0)
            fuse_kernel<false><<<1024, 256, 0, stream>>>(
                out3, s2b, x, 614400, nullptr, obn, fbn, 0, spOut, pooled);
        else
            fuse_kernel<true><<<1024, 256, 0, stream>>>(
                out3, s2b, spIn, 76800, x + i * 76800,
                obn + i * 512, fbn, i * 128, spOut, pooled);
    }

    logits_kernel<<<1, 256, 0, stream>>>(pooled, fcw, fcb, (float*)d_out);
}